// Round 13
// baseline (24.574 us; speedup 1.0000x reference)
//
#include <hip/hip_runtime.h>
#include <math.h>

#define N_PTS  1000000
#define M_COMP 64
#define TILES  (N_PTS / 16)          // 62500 16-point tiles
#define NBLK   977                   // 977 blocks x 4 waves = 3908 waves
#define NWAVES (NBLK * 4)

typedef float        f32x4  __attribute__((ext_vector_type(4)));
typedef short        bf16x8 __attribute__((ext_vector_type(8)));
typedef unsigned int u32;
typedef u32          u32x4  __attribute__((ext_vector_type(4)));

__device__ __forceinline__ float exp2n(float x){ return __builtin_amdgcn_exp2f(x); }
__device__ __forceinline__ float log2n(float x){ return __builtin_amdgcn_logf(x); }
__device__ __forceinline__ u32   fbits(float x){ return __builtin_bit_cast(u32, x); }
__device__ __forceinline__ float trunch(float x){            // bf16-truncate, as f32
    return __builtin_bit_cast(float, fbits(x) & 0xffff0000u);
}
__device__ __forceinline__ u32 pk(float a, float b){          // 2x trunc-bf16 pack
    return (fbits(a) >> 16) | (fbits(b) & 0xffff0000u);
}
__device__ __forceinline__ bf16x8 frag(u32 a, u32 b, u32 c){  // [a,b,c,0] -> 8 bf16
    u32x4 t = {a, b, c, 0u};
    return __builtin_bit_cast(bf16x8, t);
}

// ---------------------------------------------------------------------------
// MFMA round. s_ij = f_i . g_j, f = [x0^2, x0x1, x1^2, x0, x1, 1] (K=6),
// g_j = 6 coefs (log2e-prescaled). Per 16-pt tile: S^T = G.F via 4x
// mfma_f32_16x16x32_bf16 (one per 16-comp group). K=32 slots hold the hi/lo
// split-product (A=[gh,gh,gl,0] x B=[fh,fl,fh,0] over 8-slot k-groups):
//   k0-5: gh.fh   k8-13: gh.fl   k16-21: gl.fh   (fl.gl ~2^-18 dropped)
// Lane mapping assumed (A: row=lane&15, k=(lane>>4)*8+e; B: col=lane&15,
// same k) matching the m89-verified C layout col=lane&15,row=(lane>>4)*4+reg.
// A-fragments (G-side) are tile-loop-invariant: built once per wave from the
// LDS coef table. Comp-sum per point: 15 lane-local adds + shfl_xor(16,32).
// Max-free logsumexp as before (quadratic <= 0, far comps flush to 0).
// ---------------------------------------------------------------------------
__global__ __launch_bounds__(256) void gm_mfma(
    const float* __restrict__ sample, // (N,2)
    const float* __restrict__ mu,     // (64,2)
    const float* __restrict__ A,      // (64,2,2)
    const float* __restrict__ w,      // (64,1)
    float* __restrict__ out)          // (N,1)
{
    __shared__ float cf[6 * M_COMP];

    const int tid = threadIdx.x;
    const float L2E = 1.4426950408889634f;
    const float LN2 = 0.6931471805599453f;

    if (tid < 64) {                       // wave 0: coefficient phase
        const int j = tid;
        const float a00 = A[j*4+0], a01 = A[j*4+1], a10 = A[j*4+2], a11 = A[j*4+3];
        const float g00 = 0.5f*(a00*a00 + a01*a01);
        const float g01 = 0.5f*(a00*a10 + a01*a11);
        const float g11 = 0.5f*(a10*a10 + a11*a11);
        const float det = g00*g11 - g01*g01;

        const float m0 = mu[j*2+0], m1 = mu[j*2+1];
        const float Gmu0 = g00*m0 + g01*m1;
        const float Gmu1 = g01*m0 + g11*m1;
        const float cst  = m0*Gmu0 + m1*Gmu1;

        const float wj = w[j];
        float mx = wj;
        #pragma unroll
        for (int m = 1; m < 64; m <<= 1)
            mx = fmaxf(mx, __shfl_xor(mx, m, 64));
        float se = exp2n((wj - mx) * L2E);
        #pragma unroll
        for (int m = 1; m < 64; m <<= 1)
            se += __shfl_xor(se, m, 64);
        const float lse  = mx + log2n(se) * LN2;
        const float wlog = wj - lse + 0.5f * log2n(det) * LN2;

        cf[0*M_COMP+j] = -g00 * L2E;        // * x0^2
        cf[1*M_COMP+j] = -(g01+g01) * L2E;  // * x0*x1
        cf[2*M_COMP+j] = -g11 * L2E;        // * x1^2
        cf[3*M_COMP+j] = (Gmu0+Gmu0) * L2E; // * x0
        cf[4*M_COMP+j] = (Gmu1+Gmu1) * L2E; // * x1
        cf[5*M_COMP+j] = (wlog - cst) * L2E;// * 1
    }
    __syncthreads();

    const int lane = tid & 63;
    const int col  = lane & 15;           // point slot / comp row within tile
    const int kg   = lane >> 4;           // k-group 0..3
    const int wid  = (blockIdx.x * 256 + tid) >> 6;   // global wave 0..3907

    // ---- A-fragments (G-side), built once per wave, loop-invariant -------
    const bool gLo = (kg == 2);
    const bool gZr = (kg == 3);
    bf16x8 Ag0, Ag1, Ag2, Ag3;
#define MKA(T, DST) {                                                        \
        const int c = col + 16*(T);                                          \
        const float g0 = cf[0*M_COMP+c], g1 = cf[1*M_COMP+c];                \
        const float g2 = cf[2*M_COMP+c], g3 = cf[3*M_COMP+c];                \
        const float g4 = cf[4*M_COMP+c], g5 = cf[5*M_COMP+c];                \
        const u32 GH0 = pk(g0,g1), GH1 = pk(g2,g3), GH2 = pk(g4,g5);         \
        const float e0 = g0-trunch(g0), e1 = g1-trunch(g1);                  \
        const float e2 = g2-trunch(g2), e3 = g3-trunch(g3);                  \
        const float e4 = g4-trunch(g4), e5 = g5-trunch(g5);                  \
        const u32 GL0 = pk(e0,e1), GL1 = pk(e2,e3), GL2 = pk(e4,e5);         \
        const u32 a0 = gZr ? 0u : (gLo ? GL0 : GH0);                         \
        const u32 a1 = gZr ? 0u : (gLo ? GL1 : GH1);                         \
        const u32 a2 = gZr ? 0u : (gLo ? GL2 : GH2);                         \
        DST = frag(a0, a1, a2); }
    MKA(0, Ag0) MKA(1, Ag1) MKA(2, Ag2) MKA(3, Ag3)
#undef MKA

    const bool bLo = (kg == 1);
    const bool bZr = (kg == 3);
    const f32x4 zero = {0.f, 0.f, 0.f, 0.f};
    const float2* s2 = (const float2*)sample;

    // ---- tile loop: wave `wid` handles tiles wid + NWAVES*i ---------------
    #pragma unroll 1
    for (int i = 0; i < 16; ++i) {
        const int tt = wid + NWAVES * i;
        if (tt >= TILES) break;           // wave-uniform exit
        const int pbase = tt * 16;

        // features of point pbase+col (replicated across the 4 k-groups)
        const float2 xy = s2[pbase + col];
        const float x0 = xy.x, x1 = xy.y;
        const float f0 = x0*x0, f1 = x0*x1, f2 = x1*x1;
        const float l0 = f0 - trunch(f0), l1 = f1 - trunch(f1);
        const float l2 = f2 - trunch(f2);
        const float l3 = x0 - trunch(x0), l4 = x1 - trunch(x1);
        const u32 H0 = pk(f0, f1), H1 = pk(f2, x0), H2 = pk(x1, 1.0f);
        const u32 L0 = pk(l0, l1), L1 = pk(l2, l3), L2 = pk(l4, 0.0f);
        const u32 b0 = bZr ? 0u : (bLo ? L0 : H0);
        const u32 b1 = bZr ? 0u : (bLo ? L1 : H1);
        const u32 b2 = bZr ? 0u : (bLo ? L2 : H2);
        const bf16x8 Bf = frag(b0, b1, b2);

        // S^T tile: 4 comp-groups x 16 points
        f32x4 c0 = __builtin_amdgcn_mfma_f32_16x16x32_bf16(Ag0, Bf, zero, 0, 0, 0);
        f32x4 c1 = __builtin_amdgcn_mfma_f32_16x16x32_bf16(Ag1, Bf, zero, 0, 0, 0);
        f32x4 c2 = __builtin_amdgcn_mfma_f32_16x16x32_bf16(Ag2, Bf, zero, 0, 0, 0);
        f32x4 c3 = __builtin_amdgcn_mfma_f32_16x16x32_bf16(Ag3, Bf, zero, 0, 0, 0);

        // exp + comp-sum: lane holds comps {16t + 4*kg + r} for point col
        float sum = 0.f;
        #pragma unroll
        for (int r = 0; r < 4; ++r)
            sum += exp2n(c0[r]) + exp2n(c1[r]) + exp2n(c2[r]) + exp2n(c3[r]);
        sum += __shfl_xor(sum, 16, 64);   // fold k-groups
        sum += __shfl_xor(sum, 32, 64);

        if (lane < 16)
            out[pbase + lane] = log2n(sum) * LN2;
    }
}

extern "C" void kernel_launch(void* const* d_in, const int* in_sizes, int n_in,
                              void* d_out, int out_size, void* d_ws, size_t ws_size,
                              hipStream_t stream)
{
    const float* sample = (const float*)d_in[0];  // (1e6, 2) f32
    const float* mu     = (const float*)d_in[1];  // (64, 2)  f32
    const float* A      = (const float*)d_in[2];  // (64,2,2) f32
    const float* w      = (const float*)d_in[3];  // (64, 1)  f32
    float* out = (float*)d_out;                   // (1e6, 1) f32

    gm_mfma<<<NBLK, 256, 0, stream>>>(sample, mu, A, w, out);
}

// Round 14
// 22.124 us; speedup vs baseline: 1.1108x; 1.1108x over previous
//
#include <hip/hip_runtime.h>
#include <math.h>

#define N_PTS  1000000
#define M_COMP 64
#define TILES  (N_PTS / 16)          // 62500 16-point tiles
#define NBLK   2048                  // 8192 waves -> ~8 waves/SIMD
#define NWAVES (NBLK * 4)
#define NITER  ((TILES + NWAVES - 1) / NWAVES)   // 8

typedef float        f32x4  __attribute__((ext_vector_type(4)));
typedef short        bf16x8 __attribute__((ext_vector_type(8)));
typedef unsigned int u32;
typedef u32          u32x4  __attribute__((ext_vector_type(4)));

__device__ __forceinline__ float exp2n(float x){ return __builtin_amdgcn_exp2f(x); }
__device__ __forceinline__ float log2n(float x){ return __builtin_amdgcn_logf(x); }
__device__ __forceinline__ u32   fbits(float x){ return __builtin_bit_cast(u32, x); }
__device__ __forceinline__ float trunch(float x){            // bf16-truncate, as f32
    return __builtin_bit_cast(float, fbits(x) & 0xffff0000u);
}
__device__ __forceinline__ u32 pk(float a, float b){          // 2x trunc-bf16 pack
    return (fbits(a) >> 16) | (fbits(b) & 0xffff0000u);
}
__device__ __forceinline__ bf16x8 frag(u32 a, u32 b, u32 c){  // [a,b,c,0] -> 8 bf16
    u32x4 t = {a, b, c, 0u};
    return __builtin_bit_cast(bf16x8, t);
}

// ---------------------------------------------------------------------------
// MFMA v2. R13 validated the math (absmax identical to fp32 path): s_ij =
// f_i . g_j with f=[x0^2,x0x1,x1^2,x0,x1,1], hi/lo split-product packed into
// the K=32 budget of mfma_f32_16x16x32_bf16 (k0-5 gh.fh, k8-13 gh.fl,
// k16-21 gl.fh), A: row=lane&15, k=(lane>>4)*8+e; C: col=lane&15,
// row=(lane>>4)*4+reg. R13's loss was scheduling, not math: 3.82 waves/SIMD
// and a serial 16-iter tile loop with a dependent point-load at the head of
// each iteration (latency fully exposed). v2: 2048 blocks (~8 waves/SIMD)
// + software-pipelined point loads (prefetch tile i+1 before computing
// tile i), 8 iterations. Compute section per tile (~270 cyc) + 8-way TLP
// now covers the load latency.
// ---------------------------------------------------------------------------
__global__ __launch_bounds__(256) void gm_mfma(
    const float* __restrict__ sample, // (N,2)
    const float* __restrict__ mu,     // (64,2)
    const float* __restrict__ A,      // (64,2,2)
    const float* __restrict__ w,      // (64,1)
    float* __restrict__ out)          // (N,1)
{
    __shared__ float cf[6 * M_COMP];

    const int tid = threadIdx.x;
    const float L2E = 1.4426950408889634f;
    const float LN2 = 0.6931471805599453f;

    if (tid < 64) {                       // wave 0: coefficient phase
        const int j = tid;
        const float a00 = A[j*4+0], a01 = A[j*4+1], a10 = A[j*4+2], a11 = A[j*4+3];
        const float g00 = 0.5f*(a00*a00 + a01*a01);
        const float g01 = 0.5f*(a00*a10 + a01*a11);
        const float g11 = 0.5f*(a10*a10 + a11*a11);
        const float det = g00*g11 - g01*g01;

        const float m0 = mu[j*2+0], m1 = mu[j*2+1];
        const float Gmu0 = g00*m0 + g01*m1;
        const float Gmu1 = g01*m0 + g11*m1;
        const float cst  = m0*Gmu0 + m1*Gmu1;

        const float wj = w[j];
        float mx = wj;
        #pragma unroll
        for (int m = 1; m < 64; m <<= 1)
            mx = fmaxf(mx, __shfl_xor(mx, m, 64));
        float se = exp2n((wj - mx) * L2E);
        #pragma unroll
        for (int m = 1; m < 64; m <<= 1)
            se += __shfl_xor(se, m, 64);
        const float lse  = mx + log2n(se) * LN2;
        const float wlog = wj - lse + 0.5f * log2n(det) * LN2;

        cf[0*M_COMP+j] = -g00 * L2E;        // * x0^2
        cf[1*M_COMP+j] = -(g01+g01) * L2E;  // * x0*x1
        cf[2*M_COMP+j] = -g11 * L2E;        // * x1^2
        cf[3*M_COMP+j] = (Gmu0+Gmu0) * L2E; // * x0
        cf[4*M_COMP+j] = (Gmu1+Gmu1) * L2E; // * x1
        cf[5*M_COMP+j] = (wlog - cst) * L2E;// * 1
    }
    __syncthreads();

    const int lane = tid & 63;
    const int col  = lane & 15;           // point slot / comp row within tile
    const int kg   = lane >> 4;           // k-group 0..3
    const int wid  = (blockIdx.x * 256 + tid) >> 6;   // global wave id

    // ---- A-fragments (G-side), built once per wave, loop-invariant -------
    const bool gLo = (kg == 2);
    const bool gZr = (kg == 3);
    bf16x8 Ag0, Ag1, Ag2, Ag3;
#define MKA(T, DST) {                                                        \
        const int c = col + 16*(T);                                          \
        const float g0 = cf[0*M_COMP+c], g1 = cf[1*M_COMP+c];                \
        const float g2 = cf[2*M_COMP+c], g3 = cf[3*M_COMP+c];                \
        const float g4 = cf[4*M_COMP+c], g5 = cf[5*M_COMP+c];                \
        const u32 GH0 = pk(g0,g1), GH1 = pk(g2,g3), GH2 = pk(g4,g5);         \
        const float e0 = g0-trunch(g0), e1 = g1-trunch(g1);                  \
        const float e2 = g2-trunch(g2), e3 = g3-trunch(g3);                  \
        const float e4 = g4-trunch(g4), e5 = g5-trunch(g5);                  \
        const u32 GL0 = pk(e0,e1), GL1 = pk(e2,e3), GL2 = pk(e4,e5);         \
        const u32 a0 = gZr ? 0u : (gLo ? GL0 : GH0);                         \
        const u32 a1 = gZr ? 0u : (gLo ? GL1 : GH1);                         \
        const u32 a2 = gZr ? 0u : (gLo ? GL2 : GH2);                         \
        DST = frag(a0, a1, a2); }
    MKA(0, Ag0) MKA(1, Ag1) MKA(2, Ag2) MKA(3, Ag3)
#undef MKA

    const bool bLo = (kg == 1);
    const bool bZr = (kg == 3);
    const f32x4 zero = {0.f, 0.f, 0.f, 0.f};
    const float2* s2 = (const float2*)sample;

    // ---- software-pipelined tile loop ------------------------------------
    // wave `wid` handles tiles wid + NWAVES*i, i = 0..NITER-1; the point
    // data for tile i+1 is loaded before tile i's compute so its latency
    // hides under the MFMA/exp/reduce work (plus 8-way wave TLP).
    float2 xy_cur = {0.f, 0.f};
    if (wid < TILES) xy_cur = s2[wid * 16 + col];

    #pragma unroll 1
    for (int i = 0; i < NITER; ++i) {
        const int tt = wid + NWAVES * i;
        const int tn = tt + NWAVES;
        float2 xy_nxt = {0.f, 0.f};
        if (tn < TILES) xy_nxt = s2[tn * 16 + col];   // prefetch (next iter)

        if (tt < TILES) {                              // wave-uniform guard
            const float x0 = xy_cur.x, x1 = xy_cur.y;
            const float f0 = x0*x0, f1 = x0*x1, f2 = x1*x1;
            const float l0 = f0 - trunch(f0), l1 = f1 - trunch(f1);
            const float l2 = f2 - trunch(f2);
            const float l3 = x0 - trunch(x0), l4 = x1 - trunch(x1);
            const u32 H0 = pk(f0, f1), H1 = pk(f2, x0), H2 = pk(x1, 1.0f);
            const u32 L0 = pk(l0, l1), L1 = pk(l2, l3), L2 = pk(l4, 0.0f);
            const u32 b0 = bZr ? 0u : (bLo ? L0 : H0);
            const u32 b1 = bZr ? 0u : (bLo ? L1 : H1);
            const u32 b2 = bZr ? 0u : (bLo ? L2 : H2);
            const bf16x8 Bf = frag(b0, b1, b2);

            // S^T tile: 4 comp-groups x 16 points
            f32x4 c0 = __builtin_amdgcn_mfma_f32_16x16x32_bf16(Ag0, Bf, zero, 0, 0, 0);
            f32x4 c1 = __builtin_amdgcn_mfma_f32_16x16x32_bf16(Ag1, Bf, zero, 0, 0, 0);
            f32x4 c2 = __builtin_amdgcn_mfma_f32_16x16x32_bf16(Ag2, Bf, zero, 0, 0, 0);
            f32x4 c3 = __builtin_amdgcn_mfma_f32_16x16x32_bf16(Ag3, Bf, zero, 0, 0, 0);

            // exp + comp-sum: lane holds comps {16g + 4*kg + r} of point col
            float s0 = 0.f, s1 = 0.f, s2a = 0.f, s3 = 0.f;
            #pragma unroll
            for (int r = 0; r < 4; ++r) {
                s0 += exp2n(c0[r]);
                s1 += exp2n(c1[r]);
                s2a += exp2n(c2[r]);
                s3 += exp2n(c3[r]);
            }
            float sum = (s0 + s1) + (s2a + s3);
            sum += __shfl_xor(sum, 16, 64);   // fold k-groups
            sum += __shfl_xor(sum, 32, 64);

            if (lane < 16)
                out[tt * 16 + lane] = log2n(sum) * LN2;
        }
        xy_cur = xy_nxt;
    }
}

extern "C" void kernel_launch(void* const* d_in, const int* in_sizes, int n_in,
                              void* d_out, int out_size, void* d_ws, size_t ws_size,
                              hipStream_t stream)
{
    const float* sample = (const float*)d_in[0];  // (1e6, 2) f32
    const float* mu     = (const float*)d_in[1];  // (64, 2)  f32
    const float* A      = (const float*)d_in[2];  // (64,2,2) f32
    const float* w      = (const float*)d_in[3];  // (64, 1)  f32
    float* out = (float*)d_out;                   // (1e6, 1) f32

    gm_mfma<<<NBLK, 256, 0, stream>>>(sample, mu, A, w, out);
}

// Round 15
// 17.562 us; speedup vs baseline: 1.3993x; 1.2598x over previous
//
#include <hip/hip_runtime.h>
#include <math.h>

#define N_PTS  1000000
#define M_COMP 64

typedef float v2f __attribute__((ext_vector_type(2)));

__device__ __forceinline__ float exp2n(float x) { return __builtin_amdgcn_exp2f(x); }
__device__ __forceinline__ float log2n(float x) { return __builtin_amdgcn_logf(x); }

// ---------------------------------------------------------------------------
// SESSION-BEST kernel (R12, 17.52us) — reinstated after the MFMA arc (R13/
// R14: numerically exact via hi/lo bf16 split-product, but 22-25us: the
// per-tile pack/select/reduce overhead exceeds the ~5us of fp32 fma it
// saves at this shape, K=6).
//
// Structure: single fused kernel.
//  - wave 0: per-component coefficients of the quadratic
//      s_ij = -g00 x0^2 - 2g01 x0x1 - g11 x1^2 + 2Gmu0 x0 + 2Gmu1 x1
//             + (wlog - mu^T G mu),  pre-scaled by log2(e)
//    log_softmax via 64-lane shfl butterflies, native exp2/log2. LDS SoA.
//  - all threads: 2 points/thread (one float4 load), comp-packed v2f math
//    (coef pairs = register-adjacent float4 halves, zero-cost operands;
//    point values are comp-loop-invariant splats), native v_exp_f32,
//    max-free logsumexp (quadratic <= 0, wlog ~ 0.5; far comps flush to 0
//    harmlessly in fp32), final log via v_log_f32.
//
// Measured plateau ledger (all within noise of 17.5us): pts/thread 2 vs 4,
// occupancy 3.8 vs 7.6 waves/SIMD, LDS reg-double-buffer, SGPR coef
// delivery, packing axis, software exp2. Structural floor: 384e6 fp32 fma
// slots + 64e6 mandatory exps ~= 8us pipe + ~4.5us launch/traffic.
// ---------------------------------------------------------------------------
__global__ __launch_bounds__(256) void gm_fused(
    const float* __restrict__ sample, // (N,2)
    const float* __restrict__ mu,     // (64,2)
    const float* __restrict__ A,      // (64,2,2)
    const float* __restrict__ w,      // (64,1)
    float* __restrict__ out)          // (N,1)
{
    __shared__ float cf[6 * M_COMP];

    const int tid = threadIdx.x;
    const float L2E = 1.4426950408889634f;
    const float LN2 = 0.6931471805599453f;

    if (tid < 64) {                       // wave 0: coefficient phase
        const int j = tid;
        const float a00 = A[j*4+0], a01 = A[j*4+1], a10 = A[j*4+2], a11 = A[j*4+3];
        const float g00 = 0.5f*(a00*a00 + a01*a01);
        const float g01 = 0.5f*(a00*a10 + a01*a11);
        const float g11 = 0.5f*(a10*a10 + a11*a11);
        const float det = g00*g11 - g01*g01;

        const float m0 = mu[j*2+0], m1 = mu[j*2+1];
        const float Gmu0 = g00*m0 + g01*m1;
        const float Gmu1 = g01*m0 + g11*m1;
        const float cst  = m0*Gmu0 + m1*Gmu1;

        const float wj = w[j];
        float mx = wj;
        #pragma unroll
        for (int m = 1; m < 64; m <<= 1)
            mx = fmaxf(mx, __shfl_xor(mx, m, 64));
        float se = exp2n((wj - mx) * L2E);
        #pragma unroll
        for (int m = 1; m < 64; m <<= 1)
            se += __shfl_xor(se, m, 64);
        const float lse  = mx + log2n(se) * LN2;
        const float wlog = wj - lse + 0.5f * log2n(det) * LN2;

        cf[0*M_COMP+j] = -g00 * L2E;
        cf[1*M_COMP+j] = -(g01+g01) * L2E;
        cf[2*M_COMP+j] = -g11 * L2E;
        cf[3*M_COMP+j] = (Gmu0+Gmu0) * L2E;
        cf[4*M_COMP+j] = (Gmu1+Gmu1) * L2E;
        cf[5*M_COMP+j] = (wlog - cst) * L2E;
    }
    __syncthreads();

    const int t  = blockIdx.x * 256 + tid;   // 2 points per thread
    const int p0 = t * 2;
    const bool ok = p0 < N_PTS;              // N%2==0
    const int  pl = ok ? p0 : 0;             // clamp OOB, keep wave intact

    const float4 q = ((const float4*)sample)[pl >> 1];  // points p0, p0+1

    // Per-point values, hoisted (comp-loop-invariant), static unroll only.
    const float x0v[2]  = {q.x, q.z};
    const float x1v[2]  = {q.y, q.w};
    float xx0v[2], x01v[2], xx1v[2];
    #pragma unroll
    for (int p = 0; p < 2; ++p) {
        xx0v[p] = x0v[p]*x0v[p];
        x01v[p] = x0v[p]*x1v[p];
        xx1v[p] = x1v[p]*x1v[p];
    }

    v2f acc[2] = {{0.f,0.f},{0.f,0.f}};      // [point] over comp-pair

    #pragma unroll 2
    for (int jc = 0; jc < M_COMP; jc += 4) {
        const float4 c0 = *(const float4*)&cf[0*M_COMP+jc];
        const float4 c1 = *(const float4*)&cf[1*M_COMP+jc];
        const float4 c2 = *(const float4*)&cf[2*M_COMP+jc];
        const float4 c3 = *(const float4*)&cf[3*M_COMP+jc];
        const float4 c4 = *(const float4*)&cf[4*M_COMP+jc];
        const float4 c5 = *(const float4*)&cf[5*M_COMP+jc];

        // zero-cost v2f views of the float4 halves (register-adjacent)
        const v2f c0lo = {c0.x, c0.y}, c0hi = {c0.z, c0.w};
        const v2f c1lo = {c1.x, c1.y}, c1hi = {c1.z, c1.w};
        const v2f c2lo = {c2.x, c2.y}, c2hi = {c2.z, c2.w};
        const v2f c3lo = {c3.x, c3.y}, c3hi = {c3.z, c3.w};
        const v2f c4lo = {c4.x, c4.y}, c4hi = {c4.z, c4.w};
        const v2f c5lo = {c5.x, c5.y}, c5hi = {c5.z, c5.w};

        #pragma unroll
        for (int p = 0; p < 2; ++p) {
            const v2f X0  = {x0v[p],  x0v[p]};   // hoisted across jc loop
            const v2f X1  = {x1v[p],  x1v[p]};
            const v2f XX0 = {xx0v[p], xx0v[p]};
            const v2f X01 = {x01v[p], x01v[p]};
            const v2f XX1 = {xx1v[p], xx1v[p]};

            v2f s = c5lo;                        // comps jc, jc+1
            s = __builtin_elementwise_fma(c4lo, X1,  s);
            s = __builtin_elementwise_fma(c3lo, X0,  s);
            s = __builtin_elementwise_fma(c2lo, XX1, s);
            s = __builtin_elementwise_fma(c1lo, X01, s);
            s = __builtin_elementwise_fma(c0lo, XX0, s);
            acc[p][0] += exp2n(s[0]);
            acc[p][1] += exp2n(s[1]);

            v2f r = c5hi;                        // comps jc+2, jc+3
            r = __builtin_elementwise_fma(c4hi, X1,  r);
            r = __builtin_elementwise_fma(c3hi, X0,  r);
            r = __builtin_elementwise_fma(c2hi, XX1, r);
            r = __builtin_elementwise_fma(c1hi, X01, r);
            r = __builtin_elementwise_fma(c0hi, XX0, r);
            acc[p][0] += exp2n(r[0]);
            acc[p][1] += exp2n(r[1]);
        }
    }

    if (ok) {
        float2 o;                                // horizontal comp-pair merge
        o.x = log2n(acc[0][0] + acc[0][1]) * LN2;
        o.y = log2n(acc[1][0] + acc[1][1]) * LN2;
        *(float2*)&out[p0] = o;
    }
}

extern "C" void kernel_launch(void* const* d_in, const int* in_sizes, int n_in,
                              void* d_out, int out_size, void* d_ws, size_t ws_size,
                              hipStream_t stream)
{
    const float* sample = (const float*)d_in[0];  // (1e6, 2) f32
    const float* mu     = (const float*)d_in[1];  // (64, 2)  f32
    const float* A      = (const float*)d_in[2];  // (64,2,2) f32
    const float* w      = (const float*)d_in[3];  // (64, 1)  f32
    float* out = (float*)d_out;                   // (1e6, 1) f32

    const int blocks = (N_PTS/2 + 255) / 256;     // 1954 -> 7.6 waves/SIMD
    gm_fused<<<blocks, 256, 0, stream>>>(sample, mu, A, w, out);
}